// Round 10
// baseline (546.622 us; speedup 1.0000x reference)
//
#include <hip/hip_runtime.h>

#define D_DIM 1024
#define NROWS 8192

typedef float f32x4 __attribute__((ext_vector_type(4)));
typedef int   i32x4 __attribute__((ext_vector_type(4)));
typedef int   i32x8 __attribute__((ext_vector_type(8)));

typedef const __attribute__((address_space(1))) void* gaddr_t;
typedef __attribute__((address_space(3))) void* laddr_t;

__device__ __forceinline__ void load16_to_lds(const void* g, void* l) {
    __builtin_amdgcn_global_load_lds((gaddr_t)g, (laddr_t)l, 16, 0, 0);
}

// ---- kernel 1: fp32 row-normalize -> fp8 e4m3, one WAVE per row (no barriers).
// K is PERMUTED within each 128-element block (identically for A and B — dot
// products are K-permutation-invariant): orig k = 32s+8f+b (s=step 0..3,
// f=lane quarter 0..3, b=0..7) stored at byte (f + 4*(s>>1))*16 + (s&1)*8 + b.
// Lane l owns dest 16-B chunk at byte 16*l: chunk l = {blk=l>>3, q=(l>>2)&1,
// f=l&3} holds orig elements [base,base+8) and [base+32,base+40) with
// base = 128*blk + 64*q + 8*f. ONE coalesced 16-B store/lane; 4 float4
// loads/lane cover the row exactly once.
// Zeroes the encoded-max array, the gemm completion counter (maxenc[2*NROWS]),
// and d_out (all poisoned 0xAA before every launch). Stream order guarantees
// these stores are flushed (kernel-boundary release) before gemm starts.
__global__ __launch_bounds__(256) void normalize_rows(const float* __restrict__ ex,
                                                      const float* __restrict__ ey,
                                                      unsigned char* __restrict__ Aq,
                                                      unsigned char* __restrict__ Bq,
                                                      int* __restrict__ maxenc,
                                                      float* __restrict__ out) {
    const int wave = threadIdx.x >> 6, lane = threadIdx.x & 63;
    const int r = blockIdx.x * 4 + wave;
    if (lane == 0) maxenc[r] = 0;   // 0 < int-encoding of any (cosine+2.0) > 0
    if (blockIdx.x == 0 && threadIdx.x < 2) out[threadIdx.x] = 0.0f;
    if (blockIdx.x == 0 && threadIdx.x == 2) maxenc[2 * NROWS] = 0;  // counter

    const float* src;
    unsigned char* dst;
    if (r < NROWS) { src = ex + (size_t)r * D_DIM;           dst = Aq + (size_t)r * D_DIM; }
    else           { src = ey + (size_t)(r - NROWS) * D_DIM; dst = Bq + (size_t)(r - NROWS) * D_DIM; }

    const int base4 = (lane >> 3) * 32 + ((lane >> 2) & 1) * 16 + (lane & 3) * 2; // float4 idx of base
    float4 va = ((const float4*)src)[base4];       // elements base .. base+3
    float4 vb = ((const float4*)src)[base4 + 1];   // base+4 .. base+7
    float4 vc = ((const float4*)src)[base4 + 8];   // base+32 .. base+35
    float4 vd = ((const float4*)src)[base4 + 9];   // base+36 .. base+39

    float ss = va.x * va.x + va.y * va.y + va.z * va.z + va.w * va.w
             + vb.x * vb.x + vb.y * vb.y + vb.z * vb.z + vb.w * vb.w
             + vc.x * vc.x + vc.y * vc.y + vc.z * vc.z + vc.w * vc.w
             + vd.x * vd.x + vd.y * vd.y + vd.z * vd.z + vd.w * vd.w;
    #pragma unroll
    for (int off = 32; off; off >>= 1) ss += __shfl_xor(ss, off, 64);
    float sc = 1.0f / fmaxf(sqrtf(ss), 1e-8f);

    i32x4 o;   // v_cvt_pk_fp8_f32: RNE, saturating; |x| <= ~0.3, no overflow
    int w;
    w = __builtin_amdgcn_cvt_pk_fp8_f32(va.x * sc, va.y * sc, 0, false);
    o[0] = __builtin_amdgcn_cvt_pk_fp8_f32(va.z * sc, va.w * sc, w, true);
    w = __builtin_amdgcn_cvt_pk_fp8_f32(vb.x * sc, vb.y * sc, 0, false);
    o[1] = __builtin_amdgcn_cvt_pk_fp8_f32(vb.z * sc, vb.w * sc, w, true);
    w = __builtin_amdgcn_cvt_pk_fp8_f32(vc.x * sc, vc.y * sc, 0, false);
    o[2] = __builtin_amdgcn_cvt_pk_fp8_f32(vc.z * sc, vc.w * sc, w, true);
    w = __builtin_amdgcn_cvt_pk_fp8_f32(vd.x * sc, vd.y * sc, 0, false);
    o[3] = __builtin_amdgcn_cvt_pk_fp8_f32(vd.z * sc, vd.w * sc, w, true);
    ((i32x4*)dst)[lane] = o;
}

// ---- kernel 2: 128x128-tile fp8 MFMA GEMM (C = A . B^T), fused row/col max
// AND fused finalize (last-block reduction -> out).
// MX-scaled v_mfma_scale_f32_16x16x128_f8f6f4, unit scales (E8M0 0x7F = 2^0)
// = exact fp8 math at ~2x non-scaled rate. BK=128, single 32 KB LDS buffer,
// 2-barrier K-loop, zero bank conflicts (16-B XOR swizzle + K-permutation),
// XCD-aware 8x8 supertile block swizzle, #pragma unroll 1 + incremental
// pointers (kt-unroll balloons addressing to ~244 VGPR and spills: R11-R15).
// Structure ledger: single-buf/3 blocks/CU = 85 us (R16/R18); dbuf+syncthreads
// = 114 (R17, vmcnt(0) drain nullifies prefetch, -1 block); dbuf+counted
// vmcnt+raw barriers = 112 (R19, guide regime-gate confirmed: T4 is null at
// 2-phase/128^2 — occupancy dominates, pipelining variants at 2 blocks/CU are
// equivalent). 85 us is near this frame's structural ceiling (floors: LDS 41,
// HBM 38, MFMA 29.5 us).
// R20: fuse finalize. After the atomicMax epilogue: threadfence + counter
// atomicAdd (counter = maxenc[2*NROWS], zeroed by normalize); last block
// re-reads all 16384 maxes via atomicAdd(p,0) — RMW at the device coherent
// point, REQUIRED because per-XCD L2s are non-coherent and there is no
// kernel-boundary acquire inside the fused kernel (plain loads could hit
// stale clean lines from the harness's poison memset). Saves one kernel
// launch + inter-dispatch gap from the fixed non-gemm tail.
__global__ __launch_bounds__(256, 4) void gemm_max(const unsigned char* __restrict__ A,
                                                   const unsigned char* __restrict__ B,
                                                   int* __restrict__ rowmax,
                                                   int* __restrict__ colmax,
                                                   float* __restrict__ out) {
    __shared__ __align__(16) unsigned char Alds[128 * 128];   // 16 KB
    __shared__ __align__(16) unsigned char Blds[128 * 128];   // 16 KB

    const int bid = blockIdx.x;
    const int sgr = bid >> 6;
    const int bm  = ((sgr & 7) << 3) | ((bid >> 3) & 7);
    const int bn  = ((sgr >> 3) << 3) | (bid & 7);
    const int rowb = bm * 128;
    const int colb = bn * 128;

    const int t    = threadIdx.x;
    const int lane = t & 63;
    const int wave = t >> 6;
    const int wm = (wave & 1) * 64;       // wave row offset within tile
    const int wn = (wave >> 1) * 64;      // wave col offset within tile
    const int fr = lane & 15;             // fragment row/col index
    const int fq = lane >> 4;             // quarter: k-chunk index
    const int pos1 = (fq ^ (fr & 7)) * 16;   // swizzled LDS pos of chunk fq

    // staging: thread t stages LDS (row t>>3, pos t&7) <- global chunk (t&7)^(row&7)
    const int srow = t >> 3;
    const int scol = ((t ^ (t >> 3)) & 7) * 16;

    const unsigned char* ag = A + (size_t)(rowb + srow) * D_DIM + scol;
    const unsigned char* bg = B + (size_t)(colb + srow) * D_DIM + scol;

    f32x4 acc[4][4] = {};

    #pragma unroll 1
    for (int kt = 0; kt < D_DIM; kt += 128) {
        #pragma unroll
        for (int i = 0; i < 4; ++i)
            load16_to_lds(ag + (size_t)i * 32 * D_DIM,
                          (char*)Alds + i * 4096 + wave * 1024);
        #pragma unroll
        for (int i = 0; i < 4; ++i)
            load16_to_lds(bg + (size_t)i * 32 * D_DIM,
                          (char*)Blds + i * 4096 + wave * 1024);
        ag += 128;
        bg += 128;
        __syncthreads();

        // A fragments: 4 rows x 32 B (chunk fq then chunk fq^4, same order as B)
        i32x8 af[4];
        #pragma unroll
        for (int i = 0; i < 4; ++i) {
            i32x4 lo = *(const i32x4*)(Alds + (wm + i * 16 + fr) * 128 + pos1);
            i32x4 hi = *(const i32x4*)(Alds + (wm + i * 16 + fr) * 128 + (pos1 ^ 64));
            af[i] = __builtin_shufflevector(lo, hi, 0, 1, 2, 3, 4, 5, 6, 7);
        }
        #pragma unroll
        for (int j = 0; j < 4; ++j) {
            i32x4 lo = *(const i32x4*)(Blds + (wn + j * 16 + fr) * 128 + pos1);
            i32x4 hi = *(const i32x4*)(Blds + (wn + j * 16 + fr) * 128 + (pos1 ^ 64));
            i32x8 bf = __builtin_shufflevector(lo, hi, 0, 1, 2, 3, 4, 5, 6, 7);
            #pragma unroll
            for (int i = 0; i < 4; ++i)
                acc[i][j] = __builtin_amdgcn_mfma_scale_f32_16x16x128_f8f6f4(
                    af[i], bf, acc[i][j],
                    0, 0,                 // cbsz=0 (A: fp8 e4m3), blgp=0 (B: fp8 e4m3)
                    0, 0x7F7F7F7F,        // scale_a: every block exponent = 2^0
                    0, 0x7F7F7F7F);       // scale_b: every block exponent = 2^0
        }
        __syncthreads();
    }

    // ---- epilogue: fused max reductions.
    // C/D layout (shape-determined, m89-verified): col = lane&15, row = fq*4 + reg.
    const float SH = 2.0f;   // cosine >= -1 -> v+2 > 0 -> int-ordered float bits

    #pragma unroll
    for (int i = 0; i < 4; ++i) {
        #pragma unroll
        for (int r = 0; r < 4; ++r) {
            float m = fmaxf(fmaxf(acc[i][0][r], acc[i][1][r]),
                            fmaxf(acc[i][2][r], acc[i][3][r]));
            m = fmaxf(m, __shfl_xor(m, 1, 64));   // reduce over the 16 lanes sharing fq
            m = fmaxf(m, __shfl_xor(m, 2, 64));
            m = fmaxf(m, __shfl_xor(m, 4, 64));
            m = fmaxf(m, __shfl_xor(m, 8, 64));
            if (fr == 0) {
                int row = rowb + wm + i * 16 + fq * 4 + r;
                atomicMax(&rowmax[row], __float_as_int(m + SH));
            }
        }
    }
    #pragma unroll
    for (int j = 0; j < 4; ++j) {
        float m = -1e30f;
        #pragma unroll
        for (int i = 0; i < 4; ++i)
            #pragma unroll
            for (int r = 0; r < 4; ++r)
                m = fmaxf(m, acc[i][j][r]);
        m = fmaxf(m, __shfl_xor(m, 16, 64));      // reduce over the 4 quarters
        m = fmaxf(m, __shfl_xor(m, 32, 64));
        if (fq == 0) {
            int col = colb + wn + j * 16 + fr;
            atomicMax(&colmax[col], __float_as_int(m + SH));
        }
    }

    // ---- fused finalize: last block decodes maxes, log-prob, sums -> out.
    __threadfence();                 // this block's atomics visible device-wide
    __syncthreads();                 // all threads' atomics issued + fenced
    __shared__ int lastFlag;
    __shared__ float wsum0[4], wsum1[4];
    if (t == 0)
        lastFlag = (atomicAdd(colmax + NROWS, 1) == (int)gridDim.x - 1);
    __syncthreads();
    if (lastFlag) {
        int* enc = rowmax;           // contiguous [rowmax | colmax]
        float s0 = 0.0f, s1 = 0.0f;
        #pragma unroll 1
        for (int blk = 0; blk < 64; ++blk) {
            // atomicAdd(p,0): atomic read at the coherent point (see header)
            float v = __int_as_float(atomicAdd(&enc[blk * 256 + t], 0)) - 2.0f;
            float z = (v - 1.0f) * (1.0f / 0.3f);
            float s = -0.5f * z * z + 0.2850342711212634f; // -(log(.3)+.5*log(2pi))
            if (blk < 32) s0 += s; else s1 += s;
        }
        #pragma unroll
        for (int off = 32; off; off >>= 1) {
            s0 += __shfl_xor(s0, off, 64);
            s1 += __shfl_xor(s1, off, 64);
        }
        if (lane == 0) { wsum0[wave] = s0; wsum1[wave] = s1; }
        __syncthreads();
        if (t == 0) {
            out[0] = wsum0[0] + wsum0[1] + wsum0[2] + wsum0[3];
            out[1] = wsum1[0] + wsum1[1] + wsum1[2] + wsum1[3];
        }
    }
}

extern "C" void kernel_launch(void* const* d_in, const int* in_sizes, int n_in,
                              void* d_out, int out_size, void* d_ws, size_t ws_size,
                              hipStream_t stream) {
    const float* ex = (const float*)d_in[0];
    const float* ey = (const float*)d_in[1];
    float* out = (float*)d_out;

    char* ws = (char*)d_ws;
    unsigned char* Aq = (unsigned char*)ws;                                   // 8 MB
    unsigned char* Bq = (unsigned char*)(ws + (size_t)NROWS * D_DIM);         // 8 MB
    int* rowmax = (int*)(ws + (size_t)2 * NROWS * D_DIM);                     // 32 KB
    int* colmax = rowmax + NROWS;                                             // 32 KB (+4 B counter)

    normalize_rows<<<(2 * NROWS) / 4, 256, 0, stream>>>(ex, ey, Aq, Bq, rowmax, out);
    gemm_max<<<64 * 64, 256, 0, stream>>>(Aq, Bq, rowmax, colmax, out);
}

// Round 11
// 193.817 us; speedup vs baseline: 2.8203x; 2.8203x over previous
//
#include <hip/hip_runtime.h>

#define D_DIM 1024
#define NROWS 8192

typedef float f32x4 __attribute__((ext_vector_type(4)));
typedef int   i32x4 __attribute__((ext_vector_type(4)));
typedef int   i32x8 __attribute__((ext_vector_type(8)));

typedef const __attribute__((address_space(1))) void* gaddr_t;
typedef __attribute__((address_space(3))) void* laddr_t;

__device__ __forceinline__ void load16_to_lds(const void* g, void* l) {
    __builtin_amdgcn_global_load_lds((gaddr_t)g, (laddr_t)l, 16, 0, 0);
}

// ---- kernel 1: fp32 row-normalize -> fp8 e4m3, one WAVE per row (no barriers).
// K is PERMUTED within each 128-element block (identically for A and B — dot
// products are K-permutation-invariant): orig k = 32s+8f+b (s=step 0..3,
// f=lane quarter 0..3, b=0..7) stored at byte (f + 4*(s>>1))*16 + (s&1)*8 + b.
// Lane l owns dest 16-B chunk at byte 16*l: chunk l = {blk=l>>3, q=(l>>2)&1,
// f=l&3} holds orig elements [base,base+8) and [base+32,base+40) with
// base = 128*blk + 64*q + 8*f. ONE coalesced 16-B store/lane; 4 float4
// loads/lane cover the row exactly once.
// Zeroes the encoded-max array, the gemm completion counter (maxenc[2*NROWS]),
// and d_out (all poisoned 0xAA before every launch). Stream order guarantees
// these stores are visible (kernel-boundary release) before gemm starts.
__global__ __launch_bounds__(256) void normalize_rows(const float* __restrict__ ex,
                                                      const float* __restrict__ ey,
                                                      unsigned char* __restrict__ Aq,
                                                      unsigned char* __restrict__ Bq,
                                                      int* __restrict__ maxenc,
                                                      float* __restrict__ out) {
    const int wave = threadIdx.x >> 6, lane = threadIdx.x & 63;
    const int r = blockIdx.x * 4 + wave;
    if (lane == 0) maxenc[r] = 0;   // 0 < int-encoding of any (cosine+2.0) > 0
    if (blockIdx.x == 0 && threadIdx.x < 2) out[threadIdx.x] = 0.0f;
    if (blockIdx.x == 0 && threadIdx.x == 2) maxenc[2 * NROWS] = 0;  // counter

    const float* src;
    unsigned char* dst;
    if (r < NROWS) { src = ex + (size_t)r * D_DIM;           dst = Aq + (size_t)r * D_DIM; }
    else           { src = ey + (size_t)(r - NROWS) * D_DIM; dst = Bq + (size_t)(r - NROWS) * D_DIM; }

    const int base4 = (lane >> 3) * 32 + ((lane >> 2) & 1) * 16 + (lane & 3) * 2; // float4 idx of base
    float4 va = ((const float4*)src)[base4];       // elements base .. base+3
    float4 vb = ((const float4*)src)[base4 + 1];   // base+4 .. base+7
    float4 vc = ((const float4*)src)[base4 + 8];   // base+32 .. base+35
    float4 vd = ((const float4*)src)[base4 + 9];   // base+36 .. base+39

    float ss = va.x * va.x + va.y * va.y + va.z * va.z + va.w * va.w
             + vb.x * vb.x + vb.y * vb.y + vb.z * vb.z + vb.w * vb.w
             + vc.x * vc.x + vc.y * vc.y + vc.z * vc.z + vc.w * vc.w
             + vd.x * vd.x + vd.y * vd.y + vd.z * vd.z + vd.w * vd.w;
    #pragma unroll
    for (int off = 32; off; off >>= 1) ss += __shfl_xor(ss, off, 64);
    float sc = 1.0f / fmaxf(sqrtf(ss), 1e-8f);

    i32x4 o;   // v_cvt_pk_fp8_f32: RNE, saturating; |x| <= ~0.3, no overflow
    int w;
    w = __builtin_amdgcn_cvt_pk_fp8_f32(va.x * sc, va.y * sc, 0, false);
    o[0] = __builtin_amdgcn_cvt_pk_fp8_f32(va.z * sc, va.w * sc, w, true);
    w = __builtin_amdgcn_cvt_pk_fp8_f32(vb.x * sc, vb.y * sc, 0, false);
    o[1] = __builtin_amdgcn_cvt_pk_fp8_f32(vb.z * sc, vb.w * sc, w, true);
    w = __builtin_amdgcn_cvt_pk_fp8_f32(vc.x * sc, vc.y * sc, 0, false);
    o[2] = __builtin_amdgcn_cvt_pk_fp8_f32(vc.z * sc, vc.w * sc, w, true);
    w = __builtin_amdgcn_cvt_pk_fp8_f32(vd.x * sc, vd.y * sc, 0, false);
    o[3] = __builtin_amdgcn_cvt_pk_fp8_f32(vd.z * sc, vd.w * sc, w, true);
    ((i32x4*)dst)[lane] = o;
}

// ---- kernel 2: 128x128-tile fp8 MFMA GEMM (C = A . B^T), fused row/col max
// AND fused finalize (last-block reduction -> out).
// MX-scaled v_mfma_scale_f32_16x16x128_f8f6f4, unit scales (E8M0 0x7F = 2^0)
// = exact fp8 math at ~2x non-scaled rate. BK=128, single 32 KB LDS buffer,
// 2-barrier K-loop, zero bank conflicts (16-B XOR swizzle + K-permutation),
// XCD-aware 8x8 supertile block swizzle, #pragma unroll 1 + incremental
// pointers (kt-unroll balloons addressing to ~244 VGPR and spills: R11-R15).
// Structure ledger: single-buf/3 blocks/CU = 85 us (R16/R18); dbuf+syncthreads
// = 114 (R17); dbuf+counted vmcnt+raw barriers = 112 (R19) — T4 null at
// 2-phase/128^2, occupancy dominates. 85 us ~= this frame's ceiling.
// R20 fusion attempt: __threadfence() per block = L2-writeback -> 430 us.
// R21 fix: release via s_waitcnt vmcnt(0) ONLY. Correct because ALL data
// crossing the block boundary is written atomically (atomicMax, device-scope
// per m20, completes at the coherent point) and read atomically
// (atomicAdd(p,0) RMW at the coherent point) — no non-atomic communication,
// so no cache writeback is needed; vmcnt(0) orders this wave's atomicMax
// completion before the counter increment. Last-block reduction is fully
// unrolled (64 independent atomic reads in flight, ~3 us, vs 25 us serialized
// in R20). Flag/wsum overlaid into dead Alds -> LDS stays 32768.
__global__ __launch_bounds__(256, 4) void gemm_max(const unsigned char* __restrict__ A,
                                                   const unsigned char* __restrict__ B,
                                                   int* __restrict__ rowmax,
                                                   int* __restrict__ colmax,
                                                   float* __restrict__ out) {
    __shared__ __align__(16) unsigned char Alds[128 * 128];   // 16 KB
    __shared__ __align__(16) unsigned char Blds[128 * 128];   // 16 KB

    const int bid = blockIdx.x;
    const int sgr = bid >> 6;
    const int bm  = ((sgr & 7) << 3) | ((bid >> 3) & 7);
    const int bn  = ((sgr >> 3) << 3) | (bid & 7);
    const int rowb = bm * 128;
    const int colb = bn * 128;

    const int t    = threadIdx.x;
    const int lane = t & 63;
    const int wave = t >> 6;
    const int wm = (wave & 1) * 64;       // wave row offset within tile
    const int wn = (wave >> 1) * 64;      // wave col offset within tile
    const int fr = lane & 15;             // fragment row/col index
    const int fq = lane >> 4;             // quarter: k-chunk index
    const int pos1 = (fq ^ (fr & 7)) * 16;   // swizzled LDS pos of chunk fq

    // staging: thread t stages LDS (row t>>3, pos t&7) <- global chunk (t&7)^(row&7)
    const int srow = t >> 3;
    const int scol = ((t ^ (t >> 3)) & 7) * 16;

    const unsigned char* ag = A + (size_t)(rowb + srow) * D_DIM + scol;
    const unsigned char* bg = B + (size_t)(colb + srow) * D_DIM + scol;

    f32x4 acc[4][4] = {};

    #pragma unroll 1
    for (int kt = 0; kt < D_DIM; kt += 128) {
        #pragma unroll
        for (int i = 0; i < 4; ++i)
            load16_to_lds(ag + (size_t)i * 32 * D_DIM,
                          (char*)Alds + i * 4096 + wave * 1024);
        #pragma unroll
        for (int i = 0; i < 4; ++i)
            load16_to_lds(bg + (size_t)i * 32 * D_DIM,
                          (char*)Blds + i * 4096 + wave * 1024);
        ag += 128;
        bg += 128;
        __syncthreads();

        // A fragments: 4 rows x 32 B (chunk fq then chunk fq^4, same order as B)
        i32x8 af[4];
        #pragma unroll
        for (int i = 0; i < 4; ++i) {
            i32x4 lo = *(const i32x4*)(Alds + (wm + i * 16 + fr) * 128 + pos1);
            i32x4 hi = *(const i32x4*)(Alds + (wm + i * 16 + fr) * 128 + (pos1 ^ 64));
            af[i] = __builtin_shufflevector(lo, hi, 0, 1, 2, 3, 4, 5, 6, 7);
        }
        #pragma unroll
        for (int j = 0; j < 4; ++j) {
            i32x4 lo = *(const i32x4*)(Blds + (wn + j * 16 + fr) * 128 + pos1);
            i32x4 hi = *(const i32x4*)(Blds + (wn + j * 16 + fr) * 128 + (pos1 ^ 64));
            i32x8 bf = __builtin_shufflevector(lo, hi, 0, 1, 2, 3, 4, 5, 6, 7);
            #pragma unroll
            for (int i = 0; i < 4; ++i)
                acc[i][j] = __builtin_amdgcn_mfma_scale_f32_16x16x128_f8f6f4(
                    af[i], bf, acc[i][j],
                    0, 0,                 // cbsz=0 (A: fp8 e4m3), blgp=0 (B: fp8 e4m3)
                    0, 0x7F7F7F7F,        // scale_a: every block exponent = 2^0
                    0, 0x7F7F7F7F);       // scale_b: every block exponent = 2^0
        }
        __syncthreads();
    }

    // ---- epilogue: fused max reductions.
    // C/D layout (shape-determined, m89-verified): col = lane&15, row = fq*4 + reg.
    const float SH = 2.0f;   // cosine >= -1 -> v+2 > 0 -> int-ordered float bits

    #pragma unroll
    for (int i = 0; i < 4; ++i) {
        #pragma unroll
        for (int r = 0; r < 4; ++r) {
            float m = fmaxf(fmaxf(acc[i][0][r], acc[i][1][r]),
                            fmaxf(acc[i][2][r], acc[i][3][r]));
            m = fmaxf(m, __shfl_xor(m, 1, 64));   // reduce over the 16 lanes sharing fq
            m = fmaxf(m, __shfl_xor(m, 2, 64));
            m = fmaxf(m, __shfl_xor(m, 4, 64));
            m = fmaxf(m, __shfl_xor(m, 8, 64));
            if (fr == 0) {
                int row = rowb + wm + i * 16 + fq * 4 + r;
                atomicMax(&rowmax[row], __float_as_int(m + SH));
            }
        }
    }
    #pragma unroll
    for (int j = 0; j < 4; ++j) {
        float m = -1e30f;
        #pragma unroll
        for (int i = 0; i < 4; ++i)
            #pragma unroll
            for (int r = 0; r < 4; ++r)
                m = fmaxf(m, acc[i][j][r]);
        m = fmaxf(m, __shfl_xor(m, 16, 64));      // reduce over the 4 quarters
        m = fmaxf(m, __shfl_xor(m, 32, 64));
        if (fq == 0) {
            int col = colb + wn + j * 16 + fr;
            atomicMax(&colmax[col], __float_as_int(m + SH));
        }
    }

    // ---- fused finalize: last block decodes maxes, log-prob, sums -> out.
    // Release: wave-local vmcnt drain (atomics complete at coherent point).
    asm volatile("s_waitcnt vmcnt(0)" ::: "memory");
    __syncthreads();                       // all waves of this block drained
    volatile int* flagp = (volatile int*)Alds;      // overlay dead LDS
    float* ws0 = (float*)(Alds + 16);
    float* ws1 = (float*)(Alds + 32);
    if (t == 0)
        *flagp = (atomicAdd(colmax + NROWS, 1) == (int)gridDim.x - 1);
    __syncthreads();
    if (*flagp) {
        int* enc = rowmax;                 // contiguous [rowmax | colmax]
        float s0 = 0.0f, s1 = 0.0f;
        #pragma unroll                     // full unroll: 64 atomics in flight
        for (int blk = 0; blk < 64; ++blk) {
            // atomicAdd(p,0): atomic read at the device coherent point
            float v = __int_as_float(atomicAdd(&enc[blk * 256 + t], 0)) - 2.0f;
            float z = (v - 1.0f) * (1.0f / 0.3f);
            float s = -0.5f * z * z + 0.2850342711212634f; // -(log(.3)+.5*log(2pi))
            if (blk < 32) s0 += s; else s1 += s;
        }
        #pragma unroll
        for (int off = 32; off; off >>= 1) {
            s0 += __shfl_xor(s0, off, 64);
            s1 += __shfl_xor(s1, off, 64);
        }
        if (lane == 0) { ws0[wave] = s0; ws1[wave] = s1; }
        __syncthreads();
        if (t == 0) {
            out[0] = ws0[0] + ws0[1] + ws0[2] + ws0[3];
            out[1] = ws1[0] + ws1[1] + ws1[2] + ws1[3];
        }
    }
}

extern "C" void kernel_launch(void* const* d_in, const int* in_sizes, int n_in,
                              void* d_out, int out_size, void* d_ws, size_t ws_size,
                              hipStream_t stream) {
    const float* ex = (const float*)d_in[0];
    const float* ey = (const float*)d_in[1];
    float* out = (float*)d_out;

    char* ws = (char*)d_ws;
    unsigned char* Aq = (unsigned char*)ws;                                   // 8 MB
    unsigned char* Bq = (unsigned char*)(ws + (size_t)NROWS * D_DIM);         // 8 MB
    int* rowmax = (int*)(ws + (size_t)2 * NROWS * D_DIM);                     // 32 KB
    int* colmax = rowmax + NROWS;                                             // 32 KB (+4 B counter)

    normalize_rows<<<(2 * NROWS) / 4, 256, 0, stream>>>(ex, ey, Aq, Bq, rowmax, out);
    gemm_max<<<64 * 64, 256, 0, stream>>>(Aq, Bq, rowmax, colmax, out);
}

// Round 12
// 167.531 us; speedup vs baseline: 3.2628x; 1.1569x over previous
//
#include <hip/hip_runtime.h>

#define D_DIM 1024
#define NROWS 8192

typedef float f32x4 __attribute__((ext_vector_type(4)));
typedef int   i32x4 __attribute__((ext_vector_type(4)));
typedef int   i32x8 __attribute__((ext_vector_type(8)));

typedef const __attribute__((address_space(1))) void* gaddr_t;
typedef __attribute__((address_space(3))) void* laddr_t;

__device__ __forceinline__ void load16_to_lds(const void* g, void* l) {
    __builtin_amdgcn_global_load_lds((gaddr_t)g, (laddr_t)l, 16, 0, 0);
}

// ---- kernel 1: fp32 row-normalize -> fp8 e4m3, one WAVE per row (no barriers).
// K is PERMUTED within each 128-element block (identically for A and B — dot
// products are K-permutation-invariant): orig k = 32s+8f+b (s=step 0..3,
// f=lane quarter 0..3, b=0..7) stored at byte (f + 4*(s>>1))*16 + (s&1)*8 + b.
// Lane l owns dest 16-B chunk at byte 16*l; 4 coalesced float4 loads/lane
// cover the row exactly once; ONE coalesced 16-B store/lane.
// Zeroes the encoded-max array and d_out (poisoned 0xAA every launch).
__global__ __launch_bounds__(256) void normalize_rows(const float* __restrict__ ex,
                                                      const float* __restrict__ ey,
                                                      unsigned char* __restrict__ Aq,
                                                      unsigned char* __restrict__ Bq,
                                                      int* __restrict__ maxenc,
                                                      float* __restrict__ out) {
    const int wave = threadIdx.x >> 6, lane = threadIdx.x & 63;
    const int r = blockIdx.x * 4 + wave;
    if (lane == 0) maxenc[r] = 0;   // 0 < int-encoding of any (cosine+2.0) > 0
    if (blockIdx.x == 0 && threadIdx.x < 2) out[threadIdx.x] = 0.0f;

    const float* src;
    unsigned char* dst;
    if (r < NROWS) { src = ex + (size_t)r * D_DIM;           dst = Aq + (size_t)r * D_DIM; }
    else           { src = ey + (size_t)(r - NROWS) * D_DIM; dst = Bq + (size_t)(r - NROWS) * D_DIM; }

    const int base4 = (lane >> 3) * 32 + ((lane >> 2) & 1) * 16 + (lane & 3) * 2; // float4 idx of base
    float4 va = ((const float4*)src)[base4];       // elements base .. base+3
    float4 vb = ((const float4*)src)[base4 + 1];   // base+4 .. base+7
    float4 vc = ((const float4*)src)[base4 + 8];   // base+32 .. base+35
    float4 vd = ((const float4*)src)[base4 + 9];   // base+36 .. base+39

    float ss = va.x * va.x + va.y * va.y + va.z * va.z + va.w * va.w
             + vb.x * vb.x + vb.y * vb.y + vb.z * vb.z + vb.w * vb.w
             + vc.x * vc.x + vc.y * vc.y + vc.z * vc.z + vc.w * vc.w
             + vd.x * vd.x + vd.y * vd.y + vd.z * vd.z + vd.w * vd.w;
    #pragma unroll
    for (int off = 32; off; off >>= 1) ss += __shfl_xor(ss, off, 64);
    float sc = 1.0f / fmaxf(sqrtf(ss), 1e-8f);

    i32x4 o;   // v_cvt_pk_fp8_f32: RNE, saturating; |x| <= ~0.3, no overflow
    int w;
    w = __builtin_amdgcn_cvt_pk_fp8_f32(va.x * sc, va.y * sc, 0, false);
    o[0] = __builtin_amdgcn_cvt_pk_fp8_f32(va.z * sc, va.w * sc, w, true);
    w = __builtin_amdgcn_cvt_pk_fp8_f32(vb.x * sc, vb.y * sc, 0, false);
    o[1] = __builtin_amdgcn_cvt_pk_fp8_f32(vb.z * sc, vb.w * sc, w, true);
    w = __builtin_amdgcn_cvt_pk_fp8_f32(vc.x * sc, vc.y * sc, 0, false);
    o[2] = __builtin_amdgcn_cvt_pk_fp8_f32(vc.z * sc, vc.w * sc, w, true);
    w = __builtin_amdgcn_cvt_pk_fp8_f32(vd.x * sc, vd.y * sc, 0, false);
    o[3] = __builtin_amdgcn_cvt_pk_fp8_f32(vd.z * sc, vd.w * sc, w, true);
    ((i32x4*)dst)[lane] = o;
}

// ---- kernel 2: 128x256-tile fp8 MFMA GEMM (C = A . B^T) with fused row/col max.
// MX-scaled v_mfma_scale_f32_16x16x128_f8f6f4, unit scales (E8M0 0x7F = 2^0)
// = exact fp8 math at ~2x non-scaled rate. BK=128, single LDS buffer (16 KB A
// + 32 KB B), 2-barrier K-loop, zero bank conflicts (16-B XOR swizzle +
// K-permutation), XCD-aware supertile block swizzle, #pragma unroll 1 +
// incremental pointers (kt-unroll balloons addressing -> spills, R11-R15).
// Ledger: 128^2@256thr single-buf = 85 us / 12 waves/CU (R16/R18); all
// intra-block pipelining variants (dbuf, counted-vmcnt) null or regress at
// this structure (R17/R19) — latency/TLP-bound, no pipe saturated.
// R21 fused-finalize: +18 us/dispatch, tail unchanged -> unfused (the ~90 us
// non-gemm residual is normalize + harness overhead, NOT the finalize launch).
// R22: raise TLP via tile geometry, keeping the PROVEN per-wave register
// shape (64x64 output, acc 64 AGPR + ~64 arch). 512 thr = 8 waves (2M x 4N),
// tile 128x256, LDS 48 KB -> VGPR-bound 2 blocks/CU = 16 waves/CU (vs 12).
// Per-wave ds_read/MFMA identical; staging 6 loads/thread (vs 8); ~25% less
// logical fetch (B-panel reuse); half the rowmax atomics.
// Staging map (lane-linear, required by global_load_lds): thread t, iter i:
// dest = wave*1024 + lane*16 + i*8192 = (srow + 64*i)*128 + pos*16 with
// srow = t>>3, pos = t&7; source col ((t^(t>>3))&7)*16 is invariant under
// row+64 (64 = 0 mod 8), so the XOR-swizzle contract is preserved.
__global__ __launch_bounds__(512, 4) void gemm_max(const unsigned char* __restrict__ A,
                                                   const unsigned char* __restrict__ B,
                                                   int* __restrict__ rowmax,
                                                   int* __restrict__ colmax) {
    __shared__ __align__(16) unsigned char Alds[128 * 128];   // 16 KB
    __shared__ __align__(16) unsigned char Blds[256 * 128];   // 32 KB

    // grid 64(M) x 32(N) = 2048 blocks; 8x8 supertiles (bijective: 5+3+3 bits)
    const int bid = blockIdx.x;
    const int sgr = bid >> 6;
    const int bm  = ((sgr & 7) << 3) | ((bid >> 3) & 7);   // [0,64)
    const int bn  = ((sgr >> 3) << 3) | (bid & 7);         // [0,32)
    const int rowb = bm * 128;
    const int colb = bn * 256;

    const int t    = threadIdx.x;
    const int lane = t & 63;
    const int wave = t >> 6;              // [0,8)
    const int wm = (wave & 1) * 64;       // wave row offset within tile
    const int wn = (wave >> 1) * 64;      // wave col offset within tile [0,256)
    const int fr = lane & 15;             // fragment row/col index
    const int fq = lane >> 4;             // quarter: k-chunk index
    const int pos1 = (fq ^ (fr & 7)) * 16;   // swizzled LDS pos of chunk fq

    // staging: thread t stages rows srow, srow+64(,+128,+192 for B), pos t&7
    const int srow = t >> 3;                         // [0,64)
    const int scol = ((t ^ (t >> 3)) & 7) * 16;

    const unsigned char* ag = A + (size_t)(rowb + srow) * D_DIM + scol;
    const unsigned char* bg = B + (size_t)(colb + srow) * D_DIM + scol;

    f32x4 acc[4][4] = {};

    #pragma unroll 1
    for (int kt = 0; kt < D_DIM; kt += 128) {
        #pragma unroll
        for (int i = 0; i < 2; ++i)       // A: 128 rows
            load16_to_lds(ag + (size_t)i * 64 * D_DIM,
                          (char*)Alds + wave * 1024 + i * 8192);
        #pragma unroll
        for (int i = 0; i < 4; ++i)       // B: 256 rows
            load16_to_lds(bg + (size_t)i * 64 * D_DIM,
                          (char*)Blds + wave * 1024 + i * 8192);
        ag += 128;
        bg += 128;
        __syncthreads();

        // A fragments: 4 rows x 32 B (chunk fq then chunk fq^4, same order as B)
        i32x8 af[4];
        #pragma unroll
        for (int i = 0; i < 4; ++i) {
            i32x4 lo = *(const i32x4*)(Alds + (wm + i * 16 + fr) * 128 + pos1);
            i32x4 hi = *(const i32x4*)(Alds + (wm + i * 16 + fr) * 128 + (pos1 ^ 64));
            af[i] = __builtin_shufflevector(lo, hi, 0, 1, 2, 3, 4, 5, 6, 7);
        }
        #pragma unroll
        for (int j = 0; j < 4; ++j) {
            i32x4 lo = *(const i32x4*)(Blds + (wn + j * 16 + fr) * 128 + pos1);
            i32x4 hi = *(const i32x4*)(Blds + (wn + j * 16 + fr) * 128 + (pos1 ^ 64));
            i32x8 bf = __builtin_shufflevector(lo, hi, 0, 1, 2, 3, 4, 5, 6, 7);
            #pragma unroll
            for (int i = 0; i < 4; ++i)
                acc[i][j] = __builtin_amdgcn_mfma_scale_f32_16x16x128_f8f6f4(
                    af[i], bf, acc[i][j],
                    0, 0,                 // cbsz=0 (A: fp8 e4m3), blgp=0 (B: fp8 e4m3)
                    0, 0x7F7F7F7F,        // scale_a: every block exponent = 2^0
                    0, 0x7F7F7F7F);       // scale_b: every block exponent = 2^0
        }
        __syncthreads();
    }

    // ---- epilogue: fused max reductions.
    // C/D layout (shape-determined, m89-verified): col = lane&15, row = fq*4 + reg.
    const float SH = 2.0f;   // cosine >= -1 -> v+2 > 0 -> int-ordered float bits

    #pragma unroll
    for (int i = 0; i < 4; ++i) {
        #pragma unroll
        for (int r = 0; r < 4; ++r) {
            float m = fmaxf(fmaxf(acc[i][0][r], acc[i][1][r]),
                            fmaxf(acc[i][2][r], acc[i][3][r]));
            m = fmaxf(m, __shfl_xor(m, 1, 64));   // reduce over the 16 lanes sharing fq
            m = fmaxf(m, __shfl_xor(m, 2, 64));
            m = fmaxf(m, __shfl_xor(m, 4, 64));
            m = fmaxf(m, __shfl_xor(m, 8, 64));
            if (fr == 0) {
                int row = rowb + wm + i * 16 + fq * 4 + r;
                atomicMax(&rowmax[row], __float_as_int(m + SH));
            }
        }
    }
    #pragma unroll
    for (int j = 0; j < 4; ++j) {
        float m = -1e30f;
        #pragma unroll
        for (int i = 0; i < 4; ++i)
            #pragma unroll
            for (int r = 0; r < 4; ++r)
                m = fmaxf(m, acc[i][j][r]);
        m = fmaxf(m, __shfl_xor(m, 16, 64));      // reduce over the 4 quarters
        m = fmaxf(m, __shfl_xor(m, 32, 64));
        if (fq == 0) {
            int col = colb + wn + j * 16 + fr;
            atomicMax(&colmax[col], __float_as_int(m + SH));
        }
    }
}

// ---- kernel 3: decode maxes, log-prob, partial-sum, atomicAdd into out.
// 64 blocks x 256 threads over the contiguous [rowmax | colmax] array; each
// block's 256 entries lie entirely in one half. out zeroed by normalize_rows.
__global__ __launch_bounds__(256) void finalize(const int* __restrict__ maxenc,
                                                float* __restrict__ out) {
    int idx = blockIdx.x * 256 + threadIdx.x;
    float v = __int_as_float(maxenc[idx]) - 2.0f;
    float z = (v - 1.0f) * (1.0f / 0.3f);
    float s = -0.5f * z * z + 0.2850342711212634f;   // -(log(0.3)+0.5*log(2*pi))
    #pragma unroll
    for (int off = 32; off; off >>= 1) s += __shfl_xor(s, off, 64);
    __shared__ float wsum[4];
    if ((threadIdx.x & 63) == 0) wsum[threadIdx.x >> 6] = s;
    __syncthreads();
    if (threadIdx.x == 0)
        atomicAdd(&out[idx >= NROWS ? 1 : 0], wsum[0] + wsum[1] + wsum[2] + wsum[3]);
}

extern "C" void kernel_launch(void* const* d_in, const int* in_sizes, int n_in,
                              void* d_out, int out_size, void* d_ws, size_t ws_size,
                              hipStream_t stream) {
    const float* ex = (const float*)d_in[0];
    const float* ey = (const float*)d_in[1];
    float* out = (float*)d_out;

    char* ws = (char*)d_ws;
    unsigned char* Aq = (unsigned char*)ws;                                   // 8 MB
    unsigned char* Bq = (unsigned char*)(ws + (size_t)NROWS * D_DIM);         // 8 MB
    int* rowmax = (int*)(ws + (size_t)2 * NROWS * D_DIM);                     // 32 KB
    int* colmax = rowmax + NROWS;                                             // 32 KB

    normalize_rows<<<(2 * NROWS) / 4, 256, 0, stream>>>(ex, ey, Aq, Bq, rowmax, out);
    gemm_max<<<64 * 32, 512, 0, stream>>>(Aq, Bq, rowmax, colmax);
    finalize<<<64, 256, 0, stream>>>(rowmax, out);
}